// Round 5
// baseline (192.992 us; speedup 1.0000x reference)
//
#include <hip/hip_runtime.h>

#define NJ 1024
#define DETECT 0.5f
#define RESCUE 0.4975f   // 0.5 minus u8 error bound (0.00196), with margin

__device__ __forceinline__ float sample_t(int s) {
    // jnp.linspace(0,1,64) fp32 semantics (endpoint exactly 1.0)
    return (s == 63) ? 1.0f : (float)s * (1.0f / 63.0f);
}

// Tiled dword index for cell (h,w): 4x4-cell tiles, so one 64B cache line is
// a 4x4 px patch (square) instead of a 16x1 strip. Related gathers (Morton-
// adjacent lanes, consecutive samples) are ~isotropically spread in 2D, so
// square lines merge far more of them into one L2 transaction. (R2->R3: -9%)
__device__ __forceinline__ int tiled_idx(int h, int w) {
    return ((h >> 2) << 12) + ((w >> 2) << 4) + ((h & 3) << 2) + (w & 3);
}

// Exact fp32 recompute for pair (a -> weight t, b -> weight 1-t), reference op order.
__device__ __forceinline__ void exact_pair(const float2 ja, const float2 jb,
                                           const float* __restrict__ heat,
                                           float& mean_o, float& min_o)
{
    float acc = 0.0f;
    float mn  = __builtin_inff();
    for (int s = 0; s < 64; ++s) {
        const float t  = sample_t(s);
        const float om = 1.0f - t;
        float ch = __fadd_rn(__fmul_rn(ja.x, t), __fmul_rn(jb.x, om));
        float cw = __fadd_rn(__fmul_rn(ja.y, t), __fmul_rn(jb.y, om));
        ch = fminf(fmaxf(ch, 0.0f), 1023.0f);
        cw = fminf(fmaxf(cw, 0.0f), 1023.0f);
        const float hf = floorf(ch), hc = ceilf(ch);
        const float wf = floorf(cw), wc = ceilf(cw);
        const int hfi = (int)hf, hci = (int)hc;
        const int wfi = (int)wf, wci = (int)wc;
        const float a00 = heat[(hfi << 10) + wfi];
        const float a01 = heat[(hfi << 10) + wci];
        const float a10 = heat[(hci << 10) + wfi];
        const float a11 = heat[(hci << 10) + wci];
        const float t1 = __fmul_rn(__fmul_rn(a00, __fsub_rn(hc, ch)), __fsub_rn(wc, cw));
        const float t2 = __fmul_rn(__fmul_rn(a01, __fsub_rn(hc, ch)), __fsub_rn(cw, wf));
        const float t3 = __fmul_rn(__fmul_rn(a10, __fsub_rn(ch, hf)), __fsub_rn(wc, cw));
        const float t4 = __fmul_rn(__fmul_rn(a11, __fsub_rn(ch, hf)), __fsub_rn(cw, wf));
        const float feat = __fadd_rn(__fadd_rn(__fadd_rn(t1, t2), t3), t4);
        acc += feat;
        mn = fminf(mn, feat);
    }
    mean_o = acc * (1.0f / 64.0f);
    min_o  = mn;
}

__device__ __forceinline__ unsigned int expand_bits16(unsigned int v) {
    v &= 0x0000FFFFu;
    v = (v | (v << 8)) & 0x00FF00FFu;
    v = (v | (v << 4)) & 0x0F0F0F0Fu;
    v = (v | (v << 2)) & 0x33333333u;
    v = (v | (v << 1)) & 0x55555555u;
    return v;
}

// Pack + diagonal, one dispatch (block roles uniform, no intra-block divergence):
//   blocks 0..255  : pack heat -> u8x4 corner table, ONE 4x4 TILE PER THREAD.
//                    Each thread writes one full 64B line (coalesced).
//   blocks 256..259: diagonal cells mean[i][i] via exact fp32 path (all 64
//                    samples coincide at junction i -> loads are 64x-reused,
//                    cache-hot; runs concurrently with the pack blocks).
// No dependency on the sort: diag uses original junc indices directly.
__global__ __launch_bounds__(256) void pack_diag_kernel(
    const float* __restrict__ junc, const float* __restrict__ heat,
    unsigned int* __restrict__ packed, float* __restrict__ line_out,
    float* __restrict__ mean_out)
{
    const int b = blockIdx.x;
    if (b < 256) {
        const int idx = (b << 8) + threadIdx.x;   // tile id, 0..65535
        const int th = idx >> 8;                  // tile row
        const int tw = idx & 255;                 // tile col
        const int h0 = th << 2;
        const int w0 = tw << 2;

        // Load the 5x5 window (rows h0..h0+4, cols w0..w0+4, edge-clamped).
        float v[5][5];
        #pragma unroll
        for (int a = 0; a < 5; ++a) {
            const int h = (h0 + a <= 1023) ? h0 + a : 1023;
            const float* row = heat + (h << 10);
            const float4 f4 = *(const float4*)(row + w0);
            v[a][0] = f4.x; v[a][1] = f4.y; v[a][2] = f4.z; v[a][3] = f4.w;
            const int w4 = (w0 + 4 <= 1023) ? w0 + 4 : 1023;
            v[a][4] = row[w4];
        }

        unsigned int q[5][5];
        #pragma unroll
        for (int a = 0; a < 5; ++a)
            #pragma unroll
            for (int c = 0; c < 5; ++c)
                q[a][c] = (unsigned int)__float2int_rn(v[a][c] * 255.0f);

        unsigned int out[16];
        #pragma unroll
        for (int a = 0; a < 4; ++a)
            #pragma unroll
            for (int c = 0; c < 4; ++c)
                out[(a << 2) + c] = q[a][c] | (q[a][c + 1] << 8)
                                  | (q[a + 1][c] << 16) | (q[a + 1][c + 1] << 24);

        uint4* dst = (uint4*)(packed + ((th << 12) + (tw << 4)));
        dst[0] = make_uint4(out[0],  out[1],  out[2],  out[3]);
        dst[1] = make_uint4(out[4],  out[5],  out[6],  out[7]);
        dst[2] = make_uint4(out[8],  out[9],  out[10], out[11]);
        dst[3] = make_uint4(out[12], out[13], out[14], out[15]);
    } else {
        const int i = ((b - 256) << 8) + threadIdx.x;   // 0..1023
        const float2 ji = ((const float2*)junc)[i];
        float mean, mn;
        exact_pair(ji, ji, heat, mean, mn);
        mean_out[(i << 10) + i] = mean;
        line_out[(i << 10) + i] = 0.0f;   // cand_mask excludes the diagonal
    }
}

// Morton bitonic sort of the 1024 junctions (R2-proven fast path: one block,
// 1024 threads, LDS; ~55 passes). Output: sortedJ[k] = coords of k-th junction
// in Morton order, perm[k] = its original index.
__global__ __launch_bounds__(1024) void sort_kernel(
    const float* __restrict__ junc, float2* __restrict__ sortedJ,
    int* __restrict__ perm)
{
    __shared__ unsigned int sk[1024];
    __shared__ unsigned short sv[1024];
    const int t = threadIdx.x;
    const float2 jc = ((const float2*)junc)[t];
    const int mh = min(max((int)jc.x, 0), 1023);
    const int mw = min(max((int)jc.y, 0), 1023);
    sk[t] = (expand_bits16((unsigned int)mh) << 1) | expand_bits16((unsigned int)mw);
    sv[t] = (unsigned short)t;
    __syncthreads();

    for (unsigned int k = 2; k <= 1024; k <<= 1) {
        for (unsigned int s = k >> 1; s > 0; s >>= 1) {
            const int l = t ^ (int)s;
            if (l > t) {
                const unsigned int a = sk[t], b = sk[l];
                const bool up = ((t & k) == 0);
                if ((a > b) == up) {
                    sk[t] = b; sk[l] = a;
                    const unsigned short va = sv[t];
                    sv[t] = sv[l]; sv[l] = va;
                }
            }
            __syncthreads();
        }
    }
    const int src = (int)sv[t];
    perm[t] = src;
    sortedJ[t] = ((const float2*)junc)[src];
}

// One thread per pair-orientation in the SORTED band c in [1,512];
// q = r*512 + (c-1) ; jc = (r+c) mod 1024 (sorted-space indices). 2048 blocks
// exactly = 8 rounds x 256 CUs, no straggler tail (R3-proven 107 us).
// Original-space cell: (perm[r], perm[jc]). The thread writes its own cell
// AND the transpose cell for c in [1,511] (d_sorted in [513,1023] is exactly
// the set of transpose cells -> full coverage, no races); c==512 pairs are
// computed from both sides, each writing only its own orientation.
__global__ __launch_bounds__(256) void sold2_thread_kernel(
    const float2* __restrict__ sortedJ,      // [N] (h,w) Morton-ordered
    const int* __restrict__ perm,            // [N] sorted -> original index
    const float* __restrict__ heat,          // [H,W] fp32 (exact rescue path)
    const unsigned int* __restrict__ packed, // u8x4 corner blocks, 4x4-tiled
    float* __restrict__ line_out,            // [N,N] float 0/1
    float* __restrict__ mean_out)            // [N,N]
{
    const int q = blockIdx.x * 256 + threadIdx.x;   // 0 .. 1024*512-1
    const int r = q >> 9;
    const int c = 1 + (q & 511);
    const int jc = (r + c) & 1023;

    const float2 jr = sortedJ[r];
    const float2 jj = sortedJ[jc];

    float acc = 0.0f;           // in u8 counts (x255)
    float mn  = __builtin_inff();

    #pragma unroll
    for (int s0 = 0; s0 < 64; s0 += 16) {
        float chv[16], cwv[16];
        unsigned int cv[16];
        #pragma unroll
        for (int u = 0; u < 16; ++u) {
            const int s = s0 + u;
            const float t  = sample_t(s);
            const float om = 1.0f - t;
            // Reference op order: ji*t + jj*(1-t), contraction-proof.
            float ch = __fadd_rn(__fmul_rn(jr.x, t), __fmul_rn(jj.x, om));
            float cw = __fadd_rn(__fmul_rn(jr.y, t), __fmul_rn(jj.y, om));
            ch = fminf(fmaxf(ch, 0.0f), 1023.0f);
            cw = fminf(fmaxf(cw, 0.0f), 1023.0f);
            chv[u] = ch;
            cwv[u] = cw;
            const int hfi = (int)ch;   // trunc == floor for non-negative
            const int wfi = (int)cw;
            cv[u] = packed[tiled_idx(hfi, wfi)];
        }
        #pragma unroll
        for (int u = 0; u < 16; ++u) {
            const float ch = chv[u], cw = cwv[u];
            const float hf = floorf(ch), hc = ceilf(ch);
            const float wf = floorf(cw), wc = ceilf(cw);
            const float wh0 = hc - ch, wh1 = ch - hf;
            const float ww0 = wc - cw, ww1 = cw - wf;
            const unsigned int cc = cv[u];
            const float a00 = (float)(cc & 0xffu);
            const float a01 = (float)((cc >> 8) & 0xffu);
            const float a10 = (float)((cc >> 16) & 0xffu);
            const float a11 = (float)(cc >> 24);
            const float feat = a00 * (wh0 * ww0) + a01 * (wh0 * ww1)
                             + a10 * (wh1 * ww0) + a11 * (wh1 * ww1);
            acc += feat;
            mn = fminf(mn, feat);
        }
    }

    float mean = acc * (1.0f / (255.0f * 64.0f));
    const float mns = mn * (1.0f / 255.0f);

    // Conservative candidate test: exact detection implies u8 min/mean > RESCUE.
    bool det = false;
    if ((mns > RESCUE) && (mean > RESCUE)) {
        float mn2;
        exact_pair(jr, jj, heat, mean, mn2);
        det = (mean > DETECT) && (mn2 > DETECT);
    }

    const int io = perm[r];
    const int jo = perm[jc];
    const float lv = det ? 1.0f : 0.0f;

    const int p1 = (io << 10) + jo;
    // nt: streaming outputs must not evict the L2-resident packed/heat arrays.
    __builtin_nontemporal_store(mean, mean_out + p1);
    __builtin_nontemporal_store(lv,   line_out + p1);

    // Transpose cell (fused mirror): exactly the d_sorted in [513,1023] band.
    if (c != 512) {
        const int p2 = (jo << 10) + io;
        __builtin_nontemporal_store(mean, mean_out + p2);
        __builtin_nontemporal_store(lv,   line_out + p2);
    }
}

extern "C" void kernel_launch(void* const* d_in, const int* in_sizes, int n_in,
                              void* d_out, int out_size, void* d_ws, size_t ws_size,
                              hipStream_t stream) {
    const float* junc = (const float*)d_in[0];   // [1024,2] float32
    const float* heat = (const float*)d_in[1];   // [1024,1024] float32
    float* line_out = (float*)d_out;
    float* mean_out = line_out + NJ * NJ;

    unsigned int* packed = (unsigned int*)d_ws;              // 4 MB
    float2* sortedJ = (float2*)((char*)d_ws + (4u << 20));   // 8 KB
    int* perm = (int*)((char*)d_ws + (4u << 20) + 8192);     // 4 KB

    pack_diag_kernel<<<260, 256, 0, stream>>>(junc, heat, packed, line_out, mean_out);
    sort_kernel<<<1, 1024, 0, stream>>>(junc, sortedJ, perm);

    const int total = NJ * 512;                  // 524,288 threads = 2048 blocks
    sold2_thread_kernel<<<total / 256, 256, 0, stream>>>(sortedJ, perm, heat,
                                                         packed, line_out, mean_out);
}

// Round 6
// 180.094 us; speedup vs baseline: 1.0716x; 1.0716x over previous
//
#include <hip/hip_runtime.h>

#define NJ 1024
#define DETECT 0.5f
#define RESCUE 0.4975f   // 0.5 minus u8 error bound (0.00196), with margin

__device__ __forceinline__ float sample_t(int s) {
    // jnp.linspace(0,1,64) fp32 semantics (endpoint exactly 1.0)
    return (s == 63) ? 1.0f : (float)s * (1.0f / 63.0f);
}

// Tiled dword index for cell (h,w): 4x4-cell tiles, so one 64B cache line is
// a 4x4 px patch (square) instead of a 16x1 strip. (R2->R3: -9% on sold2)
__device__ __forceinline__ int tiled_idx(int h, int w) {
    return ((h >> 2) << 12) + ((w >> 2) << 4) + ((h & 3) << 2) + (w & 3);
}

// Exact fp32 recompute for pair (a -> weight t, b -> weight 1-t), reference op order.
__device__ __forceinline__ void exact_pair(const float2 ja, const float2 jb,
                                           const float* __restrict__ heat,
                                           float& mean_o, float& min_o)
{
    float acc = 0.0f;
    float mn  = __builtin_inff();
    for (int s = 0; s < 64; ++s) {
        const float t  = sample_t(s);
        const float om = 1.0f - t;
        float ch = __fadd_rn(__fmul_rn(ja.x, t), __fmul_rn(jb.x, om));
        float cw = __fadd_rn(__fmul_rn(ja.y, t), __fmul_rn(jb.y, om));
        ch = fminf(fmaxf(ch, 0.0f), 1023.0f);
        cw = fminf(fmaxf(cw, 0.0f), 1023.0f);
        const float hf = floorf(ch), hc = ceilf(ch);
        const float wf = floorf(cw), wc = ceilf(cw);
        const int hfi = (int)hf, hci = (int)hc;
        const int wfi = (int)wf, wci = (int)wc;
        const float a00 = heat[(hfi << 10) + wfi];
        const float a01 = heat[(hfi << 10) + wci];
        const float a10 = heat[(hci << 10) + wfi];
        const float a11 = heat[(hci << 10) + wci];
        const float t1 = __fmul_rn(__fmul_rn(a00, __fsub_rn(hc, ch)), __fsub_rn(wc, cw));
        const float t2 = __fmul_rn(__fmul_rn(a01, __fsub_rn(hc, ch)), __fsub_rn(cw, wf));
        const float t3 = __fmul_rn(__fmul_rn(a10, __fsub_rn(ch, hf)), __fsub_rn(wc, cw));
        const float t4 = __fmul_rn(__fmul_rn(a11, __fsub_rn(ch, hf)), __fsub_rn(cw, wf));
        const float feat = __fadd_rn(__fadd_rn(__fadd_rn(t1, t2), t3), t4);
        acc += feat;
        mn = fminf(mn, feat);
    }
    mean_o = acc * (1.0f / 64.0f);
    min_o  = mn;
}

__device__ __forceinline__ unsigned int expand_bits16(unsigned int v) {
    v &= 0x0000FFFFu;
    v = (v | (v << 8)) & 0x00FF00FFu;
    v = (v | (v << 4)) & 0x0F0F0F0Fu;
    v = (v | (v << 2)) & 0x33333333u;
    v = (v | (v << 1)) & 0x55555555u;
    return v;
}

// ONE prep dispatch, 261 blocks (roles uniform per block):
//   block  0       : approximate spatial sort. Bucket by 10-bit coarse Morton
//                    (32x32 px buckets, ~1 junction each): LDS-atomic
//                    histogram -> hierarchical prefix scan (wave shfl + 4 wave
//                    totals; ~10 steps vs bitonic's 55 barrier passes) ->
//                    scatter. Any bijective perm is exactly correct: cell
//                    (io,jo) always receives exact_pair(junc[io],junc[jo]).
//                    ~4 us, fully hidden under the pack blocks.
//   blocks 1..256  : pack heat -> u8x4 corner table, one 4x4 tile per thread
//                    (each thread writes one full 64B line, coalesced).
//   blocks 257..260: diagonal cells mean[i][i] via exact fp32 path.
__global__ __launch_bounds__(256) void prep_kernel(
    const float* __restrict__ junc, const float* __restrict__ heat,
    unsigned int* __restrict__ packed, float2* __restrict__ sortedJ,
    int* __restrict__ perm, float* __restrict__ line_out,
    float* __restrict__ mean_out)
{
    __shared__ unsigned int cnt[1024];
    __shared__ unsigned int base[1024];
    __shared__ unsigned int wtot[4];

    const int b = blockIdx.x;
    if (b == 0) {
        const int t = threadIdx.x;
        #pragma unroll
        for (int m = 0; m < 4; ++m) cnt[(m << 8) + t] = 0u;
        __syncthreads();

        unsigned int key[4], slot[4];
        #pragma unroll
        for (int m = 0; m < 4; ++m) {
            const int i = (m << 8) + t;
            const float2 jc2 = ((const float2*)junc)[i];
            const unsigned int mh = (unsigned int)(min(max((int)jc2.x, 0), 1023) >> 5);
            const unsigned int mw = (unsigned int)(min(max((int)jc2.y, 0), 1023) >> 5);
            key[m] = (expand_bits16(mh) << 1) | expand_bits16(mw);   // 10 bits
            slot[m] = atomicAdd(&cnt[key[m]], 1u);
        }
        __syncthreads();

        // Exclusive prefix sum over the 1024 bucket counts.
        unsigned int c4[4];
        unsigned int tsum = 0;
        #pragma unroll
        for (int u = 0; u < 4; ++u) { c4[u] = cnt[(t << 2) + u]; tsum += c4[u]; }
        unsigned int scan = tsum;               // wave-inclusive scan
        #pragma unroll
        for (int off = 1; off < 64; off <<= 1) {
            const unsigned int n = __shfl_up(scan, off, 64);
            if ((t & 63) >= off) scan += n;
        }
        if ((t & 63) == 63) wtot[t >> 6] = scan;
        __syncthreads();
        unsigned int wbase = 0;
        for (int wv = 0; wv < (t >> 6); ++wv) wbase += wtot[wv];
        const unsigned int ex = wbase + scan - tsum;   // excl. prefix, bucket 4t
        base[(t << 2) + 0] = ex;
        base[(t << 2) + 1] = ex + c4[0];
        base[(t << 2) + 2] = ex + c4[0] + c4[1];
        base[(t << 2) + 3] = ex + c4[0] + c4[1] + c4[2];
        __syncthreads();

        #pragma unroll
        for (int m = 0; m < 4; ++m) {
            const int i = (m << 8) + t;
            const unsigned int pos = base[key[m]] + slot[m];
            perm[pos] = i;
            sortedJ[pos] = ((const float2*)junc)[i];
        }
    } else if (b <= 256) {
        const int idx = ((b - 1) << 8) + threadIdx.x;   // tile id, 0..65535
        const int th = idx >> 8;                        // tile row
        const int tw = idx & 255;                       // tile col
        const int h0 = th << 2;
        const int w0 = tw << 2;

        float v[5][5];
        #pragma unroll
        for (int a = 0; a < 5; ++a) {
            const int h = (h0 + a <= 1023) ? h0 + a : 1023;
            const float* row = heat + (h << 10);
            const float4 f4 = *(const float4*)(row + w0);
            v[a][0] = f4.x; v[a][1] = f4.y; v[a][2] = f4.z; v[a][3] = f4.w;
            const int w4 = (w0 + 4 <= 1023) ? w0 + 4 : 1023;
            v[a][4] = row[w4];
        }

        unsigned int q[5][5];
        #pragma unroll
        for (int a = 0; a < 5; ++a)
            #pragma unroll
            for (int c = 0; c < 5; ++c)
                q[a][c] = (unsigned int)__float2int_rn(v[a][c] * 255.0f);

        unsigned int out[16];
        #pragma unroll
        for (int a = 0; a < 4; ++a)
            #pragma unroll
            for (int c = 0; c < 4; ++c)
                out[(a << 2) + c] = q[a][c] | (q[a][c + 1] << 8)
                                  | (q[a + 1][c] << 16) | (q[a + 1][c + 1] << 24);

        uint4* dst = (uint4*)(packed + ((th << 12) + (tw << 4)));
        dst[0] = make_uint4(out[0],  out[1],  out[2],  out[3]);
        dst[1] = make_uint4(out[4],  out[5],  out[6],  out[7]);
        dst[2] = make_uint4(out[8],  out[9],  out[10], out[11]);
        dst[3] = make_uint4(out[12], out[13], out[14], out[15]);
    } else {
        const int i = ((b - 257) << 8) + threadIdx.x;   // 0..1023
        const float2 ji = ((const float2*)junc)[i];
        float mean, mn;
        exact_pair(ji, ji, heat, mean, mn);
        mean_out[(i << 10) + i] = mean;
        line_out[(i << 10) + i] = 0.0f;   // cand_mask excludes the diagonal
    }
}

// One thread per pair-orientation in the SORTED band c in [1,512];
// q = r*512 + (c-1) ; jc = (r+c) mod 1024 (sorted-space indices). 2048 blocks
// exactly = 8 rounds x 256 CUs (R3/R4/R5-proven 107-110 us).
// Original-space cell: (perm[r], perm[jc]). The thread writes its own cell
// AND the transpose cell for c in [1,511] (d_sorted in [513,1023] is exactly
// the set of transpose cells -> full coverage, no races); c==512 pairs are
// computed from both sides, each writing only its own orientation.
__global__ __launch_bounds__(256) void sold2_thread_kernel(
    const float2* __restrict__ sortedJ,      // [N] (h,w) spatially ordered
    const int* __restrict__ perm,            // [N] sorted -> original index
    const float* __restrict__ heat,          // [H,W] fp32 (exact rescue path)
    const unsigned int* __restrict__ packed, // u8x4 corner blocks, 4x4-tiled
    float* __restrict__ line_out,            // [N,N] float 0/1
    float* __restrict__ mean_out)            // [N,N]
{
    const int q = blockIdx.x * 256 + threadIdx.x;   // 0 .. 1024*512-1
    const int r = q >> 9;
    const int c = 1 + (q & 511);
    const int jc = (r + c) & 1023;

    const float2 jr = sortedJ[r];
    const float2 jj = sortedJ[jc];

    float acc = 0.0f;           // in u8 counts (x255)
    float mn  = __builtin_inff();

    #pragma unroll
    for (int s0 = 0; s0 < 64; s0 += 16) {
        float chv[16], cwv[16];
        unsigned int cv[16];
        #pragma unroll
        for (int u = 0; u < 16; ++u) {
            const int s = s0 + u;
            const float t  = sample_t(s);
            const float om = 1.0f - t;
            // Reference op order: ji*t + jj*(1-t), contraction-proof.
            float ch = __fadd_rn(__fmul_rn(jr.x, t), __fmul_rn(jj.x, om));
            float cw = __fadd_rn(__fmul_rn(jr.y, t), __fmul_rn(jj.y, om));
            ch = fminf(fmaxf(ch, 0.0f), 1023.0f);
            cw = fminf(fmaxf(cw, 0.0f), 1023.0f);
            chv[u] = ch;
            cwv[u] = cw;
            const int hfi = (int)ch;   // trunc == floor for non-negative
            const int wfi = (int)cw;
            cv[u] = packed[tiled_idx(hfi, wfi)];
        }
        #pragma unroll
        for (int u = 0; u < 16; ++u) {
            const float ch = chv[u], cw = cwv[u];
            const float hf = floorf(ch), hc = ceilf(ch);
            const float wf = floorf(cw), wc = ceilf(cw);
            const float wh0 = hc - ch, wh1 = ch - hf;
            const float ww0 = wc - cw, ww1 = cw - wf;
            const unsigned int cc = cv[u];
            const float a00 = (float)(cc & 0xffu);
            const float a01 = (float)((cc >> 8) & 0xffu);
            const float a10 = (float)((cc >> 16) & 0xffu);
            const float a11 = (float)(cc >> 24);
            const float feat = a00 * (wh0 * ww0) + a01 * (wh0 * ww1)
                             + a10 * (wh1 * ww0) + a11 * (wh1 * ww1);
            acc += feat;
            mn = fminf(mn, feat);
        }
    }

    float mean = acc * (1.0f / (255.0f * 64.0f));
    const float mns = mn * (1.0f / 255.0f);

    // Conservative candidate test: exact detection implies u8 min/mean > RESCUE.
    bool det = false;
    if ((mns > RESCUE) && (mean > RESCUE)) {
        float mn2;
        exact_pair(jr, jj, heat, mean, mn2);
        det = (mean > DETECT) && (mn2 > DETECT);
    }

    const int io = perm[r];
    const int jo = perm[jc];
    const float lv = det ? 1.0f : 0.0f;

    const int p1 = (io << 10) + jo;
    // nt: streaming outputs must not evict the L2-resident packed/heat arrays.
    __builtin_nontemporal_store(mean, mean_out + p1);
    __builtin_nontemporal_store(lv,   line_out + p1);

    // Transpose cell (fused mirror): exactly the d_sorted in [513,1023] band.
    if (c != 512) {
        const int p2 = (jo << 10) + io;
        __builtin_nontemporal_store(mean, mean_out + p2);
        __builtin_nontemporal_store(lv,   line_out + p2);
    }
}

extern "C" void kernel_launch(void* const* d_in, const int* in_sizes, int n_in,
                              void* d_out, int out_size, void* d_ws, size_t ws_size,
                              hipStream_t stream) {
    const float* junc = (const float*)d_in[0];   // [1024,2] float32
    const float* heat = (const float*)d_in[1];   // [1024,1024] float32
    float* line_out = (float*)d_out;
    float* mean_out = line_out + NJ * NJ;

    unsigned int* packed = (unsigned int*)d_ws;              // 4 MB
    float2* sortedJ = (float2*)((char*)d_ws + (4u << 20));   // 8 KB
    int* perm = (int*)((char*)d_ws + (4u << 20) + 8192);     // 4 KB

    prep_kernel<<<261, 256, 0, stream>>>(junc, heat, packed, sortedJ, perm,
                                         line_out, mean_out);

    const int total = NJ * 512;                  // 524,288 threads = 2048 blocks
    sold2_thread_kernel<<<total / 256, 256, 0, stream>>>(sortedJ, perm, heat,
                                                         packed, line_out, mean_out);
}

// Round 7
// 179.114 us; speedup vs baseline: 1.0775x; 1.0055x over previous
//
#include <hip/hip_runtime.h>

#define NJ 1024
#define DETECT 0.5f
#define RESCUE 0.4975f   // 0.5 minus u8 error bound (0.00196), with margin

__device__ __forceinline__ float sample_t(int s) {
    // jnp.linspace(0,1,64) fp32 semantics (endpoint exactly 1.0)
    return (s == 63) ? 1.0f : (float)s * (1.0f / 63.0f);
}

// Tiled dword index for cell (h,w): 4x4-cell tiles, so one 64B cache line is
// a 4x4 px patch (square) instead of a 16x1 strip. (R2->R3: -9% on sold2)
__device__ __forceinline__ int tiled_idx(int h, int w) {
    return ((h >> 2) << 12) + ((w >> 2) << 4) + ((h & 3) << 2) + (w & 3);
}

// Exact fp32 recompute for pair (a -> weight t, b -> weight 1-t), reference op order.
__device__ __forceinline__ void exact_pair(const float2 ja, const float2 jb,
                                           const float* __restrict__ heat,
                                           float& mean_o, float& min_o)
{
    float acc = 0.0f;
    float mn  = __builtin_inff();
    for (int s = 0; s < 64; ++s) {
        const float t  = sample_t(s);
        const float om = 1.0f - t;
        float ch = __fadd_rn(__fmul_rn(ja.x, t), __fmul_rn(jb.x, om));
        float cw = __fadd_rn(__fmul_rn(ja.y, t), __fmul_rn(jb.y, om));
        ch = fminf(fmaxf(ch, 0.0f), 1023.0f);
        cw = fminf(fmaxf(cw, 0.0f), 1023.0f);
        const float hf = floorf(ch), hc = ceilf(ch);
        const float wf = floorf(cw), wc = ceilf(cw);
        const int hfi = (int)hf, hci = (int)hc;
        const int wfi = (int)wf, wci = (int)wc;
        const float a00 = heat[(hfi << 10) + wfi];
        const float a01 = heat[(hfi << 10) + wci];
        const float a10 = heat[(hci << 10) + wfi];
        const float a11 = heat[(hci << 10) + wci];
        const float t1 = __fmul_rn(__fmul_rn(a00, __fsub_rn(hc, ch)), __fsub_rn(wc, cw));
        const float t2 = __fmul_rn(__fmul_rn(a01, __fsub_rn(hc, ch)), __fsub_rn(cw, wf));
        const float t3 = __fmul_rn(__fmul_rn(a10, __fsub_rn(ch, hf)), __fsub_rn(wc, cw));
        const float t4 = __fmul_rn(__fmul_rn(a11, __fsub_rn(ch, hf)), __fsub_rn(cw, wf));
        const float feat = __fadd_rn(__fadd_rn(__fadd_rn(t1, t2), t3), t4);
        acc += feat;
        mn = fminf(mn, feat);
    }
    mean_o = acc * (1.0f / 64.0f);
    min_o  = mn;
}

__device__ __forceinline__ unsigned int expand_bits16(unsigned int v) {
    v &= 0x0000FFFFu;
    v = (v | (v << 8)) & 0x00FF00FFu;
    v = (v | (v << 4)) & 0x0F0F0F0Fu;
    v = (v | (v << 2)) & 0x33333333u;
    v = (v | (v << 1)) & 0x55555555u;
    return v;
}

// ONE prep dispatch, 261 blocks (roles uniform per block):
//   block  0       : EXACT Morton sort in O(10) barrier steps:
//                    (1) coarse 10-bit bucket histogram (LDS atomics) +
//                        hierarchical prefix scan (wave shfl) + scatter of
//                        30-bit unique full keys into position space;
//                    (2) wave-local bitonic refine of each 64-slot window by
//                        full key (21 shfl_xor steps, no barriers). Buckets
//                        hold ~1 junction (max ~5) so all disorder is
//                        intra-window -> exact Morton order except at 16
//                        window seams (bucket-scale, negligible).
//                    Any bijective perm is exactly correct: cell (io,jo)
//                    always receives exact_pair(junc[io],junc[jo]).
//   blocks 1..256  : pack heat -> u8x4 corner table, one 4x4 tile per thread
//                    (each thread writes one full 64B line, coalesced).
//   blocks 257..260: diagonal cells mean[i][i] via exact fp32 path.
__global__ __launch_bounds__(256) void prep_kernel(
    const float* __restrict__ junc, const float* __restrict__ heat,
    unsigned int* __restrict__ packed, float2* __restrict__ sortedJ,
    int* __restrict__ perm, float* __restrict__ line_out,
    float* __restrict__ mean_out)
{
    __shared__ unsigned int cnt[1024];   // counts, then full-key-at-position
    __shared__ unsigned int base[1024];
    __shared__ unsigned int wtot[4];

    const int b = blockIdx.x;
    if (b == 0) {
        const int t = threadIdx.x;
        #pragma unroll
        for (int m = 0; m < 4; ++m) cnt[(m << 8) + t] = 0u;
        __syncthreads();

        unsigned int fullkey[4], coarse[4], slot[4];
        #pragma unroll
        for (int m = 0; m < 4; ++m) {
            const int i = (m << 8) + t;
            const float2 jc2 = ((const float2*)junc)[i];
            const unsigned int mh = (unsigned int)min(max((int)jc2.x, 0), 1023);
            const unsigned int mw = (unsigned int)min(max((int)jc2.y, 0), 1023);
            const unsigned int mort = (expand_bits16(mh) << 1)
                                    |  expand_bits16(mw);        // 20 bits
            fullkey[m] = (mort << 10) | (unsigned int)i;         // unique 30b
            coarse[m]  = mort >> 10;   // top 10 bits = 32x32 px Morton bucket
            slot[m] = atomicAdd(&cnt[coarse[m]], 1u);
        }
        __syncthreads();

        // Exclusive prefix sum over the 1024 bucket counts.
        unsigned int c4[4];
        unsigned int tsum = 0;
        #pragma unroll
        for (int u = 0; u < 4; ++u) { c4[u] = cnt[(t << 2) + u]; tsum += c4[u]; }
        unsigned int scan = tsum;               // wave-inclusive scan
        #pragma unroll
        for (int off = 1; off < 64; off <<= 1) {
            const unsigned int n = __shfl_up(scan, off, 64);
            if ((t & 63) >= off) scan += n;
        }
        if ((t & 63) == 63) wtot[t >> 6] = scan;
        __syncthreads();
        unsigned int wbase = 0;
        for (int wv2 = 0; wv2 < (t >> 6); ++wv2) wbase += wtot[wv2];
        const unsigned int ex = wbase + scan - tsum;   // excl. prefix, bucket 4t
        base[(t << 2) + 0] = ex;
        base[(t << 2) + 1] = ex + c4[0];
        base[(t << 2) + 2] = ex + c4[0] + c4[1];
        base[(t << 2) + 3] = ex + c4[0] + c4[1] + c4[2];
        __syncthreads();

        // Scatter full keys into position space (cnt[] reused; counts dead).
        #pragma unroll
        for (int m = 0; m < 4; ++m)
            cnt[base[coarse[m]] + slot[m]] = fullkey[m];
        __syncthreads();

        // Wave-local bitonic refine: 16 windows of 64 slots; wave wv does 4.
        const int lane = t & 63;
        const int wv = t >> 6;
        for (int kk = 0; kk < 4; ++kk) {
            const int m = (kk << 2) + wv;           // window id 0..15
            unsigned int v = cnt[(m << 6) + lane];
            #pragma unroll
            for (unsigned int k2 = 2; k2 <= 64; k2 <<= 1) {
                for (unsigned int j2 = k2 >> 1; j2 > 0; j2 >>= 1) {
                    const unsigned int o = __shfl_xor(v, (int)j2, 64);
                    const bool up    = ((lane & k2) == 0);
                    const bool lower = ((lane & j2) == 0);
                    const bool keepmin = (lower == up);
                    v = keepmin ? (v < o ? v : o) : (v > o ? v : o);
                }
            }
            const int i2  = (int)(v & 1023u);
            const int pos = (m << 6) + lane;
            perm[pos] = i2;
            sortedJ[pos] = ((const float2*)junc)[i2];
        }
    } else if (b <= 256) {
        const int idx = ((b - 1) << 8) + threadIdx.x;   // tile id, 0..65535
        const int th = idx >> 8;                        // tile row
        const int tw = idx & 255;                       // tile col
        const int h0 = th << 2;
        const int w0 = tw << 2;

        float v[5][5];
        #pragma unroll
        for (int a = 0; a < 5; ++a) {
            const int h = (h0 + a <= 1023) ? h0 + a : 1023;
            const float* row = heat + (h << 10);
            const float4 f4 = *(const float4*)(row + w0);
            v[a][0] = f4.x; v[a][1] = f4.y; v[a][2] = f4.z; v[a][3] = f4.w;
            const int w4 = (w0 + 4 <= 1023) ? w0 + 4 : 1023;
            v[a][4] = row[w4];
        }

        unsigned int q[5][5];
        #pragma unroll
        for (int a = 0; a < 5; ++a)
            #pragma unroll
            for (int c = 0; c < 5; ++c)
                q[a][c] = (unsigned int)__float2int_rn(v[a][c] * 255.0f);

        unsigned int out[16];
        #pragma unroll
        for (int a = 0; a < 4; ++a)
            #pragma unroll
            for (int c = 0; c < 4; ++c)
                out[(a << 2) + c] = q[a][c] | (q[a][c + 1] << 8)
                                  | (q[a + 1][c] << 16) | (q[a + 1][c + 1] << 24);

        uint4* dst = (uint4*)(packed + ((th << 12) + (tw << 4)));
        dst[0] = make_uint4(out[0],  out[1],  out[2],  out[3]);
        dst[1] = make_uint4(out[4],  out[5],  out[6],  out[7]);
        dst[2] = make_uint4(out[8],  out[9],  out[10], out[11]);
        dst[3] = make_uint4(out[12], out[13], out[14], out[15]);
    } else {
        const int i = ((b - 257) << 8) + threadIdx.x;   // 0..1023
        const float2 ji = ((const float2*)junc)[i];
        float mean, mn;
        exact_pair(ji, ji, heat, mean, mn);
        mean_out[(i << 10) + i] = mean;
        line_out[(i << 10) + i] = 0.0f;   // cand_mask excludes the diagonal
    }
}

// One thread per pair-orientation in the SORTED band c in [1,512];
// q = r*512 + (c-1) ; jc = (r+c) mod 1024 (sorted-space indices). 2048 blocks
// exactly = 8 rounds x 256 CUs (R3/R4/R5-proven 107-110 us).
// Original-space cell: (perm[r], perm[jc]). The thread writes its own cell
// AND the transpose cell for c in [1,511] (d_sorted in [513,1023] is exactly
// the set of transpose cells -> full coverage, no races); c==512 pairs are
// computed from both sides, each writing only its own orientation.
__global__ __launch_bounds__(256) void sold2_thread_kernel(
    const float2* __restrict__ sortedJ,      // [N] (h,w) Morton-ordered
    const int* __restrict__ perm,            // [N] sorted -> original index
    const float* __restrict__ heat,          // [H,W] fp32 (exact rescue path)
    const unsigned int* __restrict__ packed, // u8x4 corner blocks, 4x4-tiled
    float* __restrict__ line_out,            // [N,N] float 0/1
    float* __restrict__ mean_out)            // [N,N]
{
    const int q = blockIdx.x * 256 + threadIdx.x;   // 0 .. 1024*512-1
    const int r = q >> 9;
    const int c = 1 + (q & 511);
    const int jc = (r + c) & 1023;

    const float2 jr = sortedJ[r];
    const float2 jj = sortedJ[jc];

    float acc = 0.0f;           // in u8 counts (x255)
    float mn  = __builtin_inff();

    #pragma unroll
    for (int s0 = 0; s0 < 64; s0 += 16) {
        float chv[16], cwv[16];
        unsigned int cv[16];
        #pragma unroll
        for (int u = 0; u < 16; ++u) {
            const int s = s0 + u;
            const float t  = sample_t(s);
            const float om = 1.0f - t;
            // Reference op order: ji*t + jj*(1-t), contraction-proof.
            float ch = __fadd_rn(__fmul_rn(jr.x, t), __fmul_rn(jj.x, om));
            float cw = __fadd_rn(__fmul_rn(jr.y, t), __fmul_rn(jj.y, om));
            ch = fminf(fmaxf(ch, 0.0f), 1023.0f);
            cw = fminf(fmaxf(cw, 0.0f), 1023.0f);
            chv[u] = ch;
            cwv[u] = cw;
            const int hfi = (int)ch;   // trunc == floor for non-negative
            const int wfi = (int)cw;
            cv[u] = packed[tiled_idx(hfi, wfi)];
        }
        #pragma unroll
        for (int u = 0; u < 16; ++u) {
            const float ch = chv[u], cw = cwv[u];
            const float hf = floorf(ch), hc = ceilf(ch);
            const float wf = floorf(cw), wc = ceilf(cw);
            const float wh0 = hc - ch, wh1 = ch - hf;
            const float ww0 = wc - cw, ww1 = cw - wf;
            const unsigned int cc = cv[u];
            const float a00 = (float)(cc & 0xffu);
            const float a01 = (float)((cc >> 8) & 0xffu);
            const float a10 = (float)((cc >> 16) & 0xffu);
            const float a11 = (float)(cc >> 24);
            const float feat = a00 * (wh0 * ww0) + a01 * (wh0 * ww1)
                             + a10 * (wh1 * ww0) + a11 * (wh1 * ww1);
            acc += feat;
            mn = fminf(mn, feat);
        }
    }

    float mean = acc * (1.0f / (255.0f * 64.0f));
    const float mns = mn * (1.0f / 255.0f);

    // Conservative candidate test: exact detection implies u8 min/mean > RESCUE.
    bool det = false;
    if ((mns > RESCUE) && (mean > RESCUE)) {
        float mn2;
        exact_pair(jr, jj, heat, mean, mn2);
        det = (mean > DETECT) && (mn2 > DETECT);
    }

    const int io = perm[r];
    const int jo = perm[jc];
    const float lv = det ? 1.0f : 0.0f;

    const int p1 = (io << 10) + jo;
    // nt: streaming outputs must not evict the L2-resident packed/heat arrays.
    __builtin_nontemporal_store(mean, mean_out + p1);
    __builtin_nontemporal_store(lv,   line_out + p1);

    // Transpose cell (fused mirror): exactly the d_sorted in [513,1023] band.
    if (c != 512) {
        const int p2 = (jo << 10) + io;
        __builtin_nontemporal_store(mean, mean_out + p2);
        __builtin_nontemporal_store(lv,   line_out + p2);
    }
}

extern "C" void kernel_launch(void* const* d_in, const int* in_sizes, int n_in,
                              void* d_out, int out_size, void* d_ws, size_t ws_size,
                              hipStream_t stream) {
    const float* junc = (const float*)d_in[0];   // [1024,2] float32
    const float* heat = (const float*)d_in[1];   // [1024,1024] float32
    float* line_out = (float*)d_out;
    float* mean_out = line_out + NJ * NJ;

    unsigned int* packed = (unsigned int*)d_ws;              // 4 MB
    float2* sortedJ = (float2*)((char*)d_ws + (4u << 20));   // 8 KB
    int* perm = (int*)((char*)d_ws + (4u << 20) + 8192);     // 4 KB

    prep_kernel<<<261, 256, 0, stream>>>(junc, heat, packed, sortedJ, perm,
                                         line_out, mean_out);

    const int total = NJ * 512;                  // 524,288 threads = 2048 blocks
    sold2_thread_kernel<<<total / 256, 256, 0, stream>>>(sortedJ, perm, heat,
                                                         packed, line_out, mean_out);
}